// Round 1
// baseline (698.592 us; speedup 1.0000x reference)
//
#include <hip/hip_runtime.h>
#include <cstddef>
#include <cstdint>

// B=2, C=8, L=512, CH=256, CW=8, NH=8, D=256, ROT=32. 128 heads total.
// head = (b*8+c)*8+n ; q/k/v bf16 [head][l][256] ; vt bf16 [head][d][512]
// conv / a2 feature layout is W-MAJOR: [bl*8+c][w*256 + h]  (h = ch index)

typedef unsigned short u16;
typedef unsigned int u32;
typedef __attribute__((ext_vector_type(8))) short short8;
typedef __attribute__((ext_vector_type(4))) float floatx4;

__device__ __forceinline__ float bf2f(u16 u) {
  union { u32 i; float f; } v; v.i = ((u32)u) << 16; return v.f;
}
__device__ __forceinline__ u16 f2bf(float f) {
  union { float f; u32 i; } v; v.f = f;
  return (u16)((v.i + 0x7fffu + ((v.i >> 16) & 1u)) >> 16);
}

// ---------------- weight convert fp32 -> bf16, layout [c][g][h] kept --------
__global__ __launch_bounds__(256) void convert_w_kernel(
    const float* __restrict__ wq, const float* __restrict__ wk,
    const float* __restrict__ wv, const float* __restrict__ wo,
    u16* __restrict__ wbf) {
  int mat = blockIdx.y;
  const float* src = (mat == 0) ? wq : (mat == 1) ? wk : (mat == 2) ? wv : wo;
  int idx = blockIdx.x * 256 + threadIdx.x;  // 524288 elems per matrix
  wbf[(size_t)mat * 524288 + idx] = f2bf(src[idx]);
}

// ------------- fused conv: q,k,v convs in one pass, bf16 w-major out --------
// block = (bl, ihalf); thread: i = ih*128 + (t&127), sh = t>>7 covers 12 (s,co)
__global__ __launch_bounds__(256) void conv_fused_kernel(
    const float* __restrict__ x,
    const float* __restrict__ wq, const float* __restrict__ wk,
    const float* __restrict__ wv,
    u16* __restrict__ oq, u16* __restrict__ ok, u16* __restrict__ ov) {
  __shared__ float wl[1728];
  int t = threadIdx.x;
  for (int i2 = t; i2 < 1728; i2 += 256)
    wl[i2] = (i2 < 576) ? wq[i2] : (i2 < 1152 ? wk[i2 - 576] : wv[i2 - 1152]);
  __syncthreads();

  int bl = blockIdx.x >> 1, ih = blockIdx.x & 1;
  int b = bl >> 9, l = bl & 511;
  int il = t & 127, sh = t >> 7;
  int i = ih * 128 + il;

  float acc[12][8];
#pragma unroll
  for (int p = 0; p < 12; ++p)
#pragma unroll
    for (int j = 0; j < 8; ++j) acc[p][j] = 0.f;

  for (int ci = 0; ci < 8; ++ci) {
    const float* xc = x + (((size_t)(b * 8 + ci) * 512 + l) << 11);
    float xr[3][10];
#pragma unroll
    for (int di = 0; di < 3; ++di) {
      int gi = i + di - 1;
      xr[di][0] = 0.f; xr[di][9] = 0.f;
      if (gi >= 0 && gi < 256) {
        float4 a = *(const float4*)(xc + gi * 8);
        float4 bq = *(const float4*)(xc + gi * 8 + 4);
        xr[di][1] = a.x; xr[di][2] = a.y; xr[di][3] = a.z; xr[di][4] = a.w;
        xr[di][5] = bq.x; xr[di][6] = bq.y; xr[di][7] = bq.z; xr[di][8] = bq.w;
      } else {
#pragma unroll
        for (int j = 1; j < 9; ++j) xr[di][j] = 0.f;
      }
    }
#pragma unroll
    for (int p = 0; p < 12; ++p) {
      int pp = sh * 12 + p;
      int s = pp >> 3, co = pp & 7;
      const float* wp = &wl[s * 576 + (co * 8 + ci) * 9];
      float w00 = wp[0], w01 = wp[1], w02 = wp[2];
      float w10 = wp[3], w11 = wp[4], w12 = wp[5];
      float w20 = wp[6], w21 = wp[7], w22 = wp[8];
#pragma unroll
      for (int j = 0; j < 8; ++j) {
        acc[p][j] += w00 * xr[0][j] + w01 * xr[0][j + 1] + w02 * xr[0][j + 2]
                   + w10 * xr[1][j] + w11 * xr[1][j + 1] + w12 * xr[1][j + 2]
                   + w20 * xr[2][j] + w21 * xr[2][j + 1] + w22 * xr[2][j + 2];
      }
    }
  }
  // w-major store: ob[(bl*8+co)*2048 + j*256 + i] ; lanes have consecutive i
#pragma unroll
  for (int p = 0; p < 12; ++p) {
    int pp = sh * 12 + p;
    int s = pp >> 3, co = pp & 7;
    u16* ob = (s == 0) ? oq : (s == 1) ? ok : ov;
    size_t base = ((size_t)(bl * 8 + co)) << 11;
#pragma unroll
    for (int j = 0; j < 8; ++j) ob[base + j * 256 + i] = f2bf(acc[p][j]);
  }
}

// ---------------- MFMA mlin: D[g][col] = sum_h W[c][g][h] * Z[c][h][col] ----
// col = bl*8+w (8192 per c). Block tile 128g x 128col, 4 waves (2x2 of 64x64).
// K=256 in 4 chunks of 64. LDS rows are 128B with 16B-slot XOR swizzle (T2).
// MODE 0: q/k head layout + rope. MODE 1: v head layout. MODE 2: fp32 out.
template <int MODE>
__global__ __launch_bounds__(256) void mlin_mfma_kernel(
    const u16* __restrict__ zin,   // [(bl*8+c)][w*256+h] bf16
    const u16* __restrict__ wbf,   // [c][g][h] bf16
    void* __restrict__ outp) {
  __shared__ u16 lds_a[8192];      // 128 g-rows x 64 k (128B rows, swizzled)
  __shared__ u16 lds_b[8192];      // 128 col-rows x 64 k

  int tid = threadIdx.x;
  int wv = tid >> 6, lane = tid & 63;
  int fn = lane & 15, fq = lane >> 4;
  int wr = wv & 1, wc = wv >> 1;

  int bx = blockIdx.x;             // 8 c x 64 cblk x 2 gblk = 1024
  int c = bx >> 7;
  int cblk = (bx >> 1) & 63;
  int gblk = bx & 1;
  int g0 = gblk * 128;
  int col0 = cblk * 128;

  const u16* wsrc = wbf + ((size_t)c << 16);

  floatx4 acc[4][4];
#pragma unroll
  for (int mf = 0; mf < 4; ++mf)
#pragma unroll
    for (int nf = 0; nf < 4; ++nf) acc[mf][nf] = (floatx4){0.f, 0.f, 0.f, 0.f};

  for (int kt = 0; kt < 4; ++kt) {
    int h0 = kt * 64;
#pragma unroll
    for (int it = 0; it < 4; ++it) {
      int li = it * 256 + tid;
      int rr = li >> 3, hs = li & 7;      // rr: g-row / col-row, hs: 16B slot
      uint4 ua = *(const uint4*)(wsrc + (size_t)(g0 + rr) * 256 + h0 + hs * 8);
      *(uint4*)((char*)lds_a + rr * 128 + ((hs ^ (rr & 7)) << 4)) = ua;
      uint4 ub = *(const uint4*)(zin +
          ((size_t)((cblk * 16 + (rr >> 3)) * 8 + c) << 11) + (rr & 7) * 256 +
          h0 + hs * 8);
      *(uint4*)((char*)lds_b + rr * 128 + ((hs ^ (rr & 7)) << 4)) = ub;
    }
    __syncthreads();
#pragma unroll
    for (int kc = 0; kc < 2; ++kc) {
      short8 af[4], bf[4];
#pragma unroll
      for (int mf = 0; mf < 4; ++mf) {
        int row = wr * 64 + mf * 16 + fn;
        af[mf] = *(const short8*)((const char*)lds_a + row * 128 +
                                  (((kc * 4 + fq) ^ (row & 7)) << 4));
      }
#pragma unroll
      for (int nf = 0; nf < 4; ++nf) {
        int row = wc * 64 + nf * 16 + fn;
        bf[nf] = *(const short8*)((const char*)lds_b + row * 128 +
                                  (((kc * 4 + fq) ^ (row & 7)) << 4));
      }
#pragma unroll
      for (int mf = 0; mf < 4; ++mf)
#pragma unroll
        for (int nf = 0; nf < 4; ++nf)
          acc[mf][nf] = __builtin_amdgcn_mfma_f32_16x16x32_bf16(
              af[mf], bf[nf], acc[mf][nf], 0, 0, 0);
    }
    __syncthreads();
  }

  // epilogue: D row = g = g0+wr*64+mf*16+fq*4+r ; D col = col0+wc*64+nf*16+fn
  if (MODE == 2) {
    float* op = (float*)outp;
#pragma unroll
    for (int nf = 0; nf < 4; ++nf) {
      int col = col0 + wc * 64 + nf * 16 + fn;
      int bl = col >> 3, w = col & 7;
      int b = bl >> 9, l = bl & 511;
      size_t rowoff = ((size_t)((b * 8 + c) * 512 + l) << 11) + w;
#pragma unroll
      for (int mf = 0; mf < 4; ++mf)
#pragma unroll
        for (int r = 0; r < 4; ++r) {
          int g = g0 + wr * 64 + mf * 16 + fq * 4 + r;
          op[rowoff + g * 8] = acc[mf][nf][r];
        }
    }
  } else {
    u16* op = (u16*)outp;
#pragma unroll
    for (int nf = 0; nf < 4; ++nf) {
      int col = col0 + wc * 64 + nf * 16 + fn;
      int bl = col >> 3, w = col & 7;
      int b = bl >> 9, l = bl & 511;
      size_t base = ((size_t)((b * 8 + c) * 8) << 17) + ((size_t)l << 8);
#pragma unroll
      for (int mf = 0; mf < 4; ++mf)
#pragma unroll
        for (int r = 0; r < 4; ++r) {
          int g = g0 + wr * 64 + mf * 16 + fq * 4 + r;
          float val = acc[mf][nf][r];
          if (MODE == 0) {
            float other = __shfl_xor(val, 1);  // partner d^1 lives in lane fn^1
            int d = ((g & 31) << 3) + w;
            if (d < 32) {
              int p = d >> 1;
              float ang = (float)l * __expf(-(float)p * 0.57564627324851142f);
              float cv = cosf(ang), sv = sinf(ang);
              val = (d & 1) ? (val * cv + other * sv) : (val * cv - other * sv);
            }
          }
          int n = g >> 5, d2 = ((g & 31) << 3) + w;
          op[base + ((size_t)n << 17) + d2] = f2bf(val);
        }
    }
  }
}

// ---------------- V transpose: vt[head][d][m] = vb[head][m][d] --------------
__global__ __launch_bounds__(256) void transpose_v_kernel(const u16* __restrict__ vb,
                                                          u16* __restrict__ vt) {
  __shared__ u16 tile[64 * 66];
  int bx = blockIdx.x;                  // head*32 + mt*4 + dt
  int head = bx >> 5, mt = (bx >> 2) & 7, dt = bx & 3;
  size_t off = (size_t)head << 17;
  int t = threadIdx.x;
#pragma unroll
  for (int it = 0; it < 2; ++it) {
    int li = it * 256 + t;
    int r = li >> 3, cs = li & 7;
    uint4 u = *(const uint4*)(vb + off + (size_t)(mt * 64 + r) * 256 + dt * 64 + cs * 8);
    *(u32*)&tile[r * 66 + cs * 8 + 0] = u.x;
    *(u32*)&tile[r * 66 + cs * 8 + 2] = u.y;
    *(u32*)&tile[r * 66 + cs * 8 + 4] = u.z;
    *(u32*)&tile[r * 66 + cs * 8 + 6] = u.w;
  }
  __syncthreads();
#pragma unroll
  for (int it = 0; it < 2; ++it) {
    int li = it * 256 + t;
    int r = li >> 3, cs = li & 7;   // r = d-local, cs = m-seg
    u16 tmp[8];
#pragma unroll
    for (int jj = 0; jj < 8; ++jj) tmp[jj] = tile[(cs * 8 + jj) * 66 + r];
    uint4 o;
    o.x = (u32)tmp[0] | ((u32)tmp[1] << 16);
    o.y = (u32)tmp[2] | ((u32)tmp[3] << 16);
    o.z = (u32)tmp[4] | ((u32)tmp[5] << 16);
    o.w = (u32)tmp[6] | ((u32)tmp[7] << 16);
    *(uint4*)(vt + off + (size_t)(dt * 64 + r) * 512 + mt * 64 + cs * 8) = o;
  }
}

// ---------------- MFMA attention: 32 q-rows per block -----------------------
__global__ __launch_bounds__(256) void attn_kernel(
    const u16* __restrict__ q, const u16* __restrict__ k,
    const u16* __restrict__ vt, const float* __restrict__ prev,
    float* __restrict__ qk_out, u16* __restrict__ a2) {
  __shared__ u16 s_bf[32 * 520];      // S / P, bf16, stride 520 (4x65 words)
  __shared__ u16 kv[32 * 288];        // K chunk (32x288) / V chunk (256x32)
  __shared__ float rinv[32];

  int head = blockIdx.x >> 4;
  int l0 = (blockIdx.x & 15) << 5;
  int b = head >> 6, c = (head >> 3) & 7, nh = head & 7;
  size_t qoff = (size_t)head << 17;
  size_t poff = (size_t)head << 18;
  int tid = threadIdx.x;
  int w = tid >> 6, lane = tid & 63;
  int fn = lane & 15, fq = lane >> 4;
  int rt = w & 1, ct = w >> 1;

  // preload Q fragments (16 rows for this wave, full K=256)
  short8 qf[8];
  const u16* qrow = q + qoff + (size_t)(l0 + rt * 16 + fn) * 256 + fq * 8;
#pragma unroll
  for (int kc = 0; kc < 8; ++kc) qf[kc] = *(const short8*)(qrow + kc * 32);

  // ---- S = QK^T/16 + prev ----
  for (int mc = 0; mc < 16; ++mc) {
    int m0 = mc * 32;
#pragma unroll
    for (int it = 0; it < 4; ++it) {
      int li = it * 256 + tid;
      int m = li >> 5, ds = li & 31;
      *(uint4*)&kv[m * 288 + ds * 8] =
          *(const uint4*)(k + qoff + (size_t)(m0 + m) * 256 + ds * 8);
    }
    __syncthreads();
    floatx4 acc = {0.f, 0.f, 0.f, 0.f};
    const u16* krow = &kv[(ct * 16 + fn) * 288 + fq * 8];
#pragma unroll
    for (int kc = 0; kc < 8; ++kc) {
      short8 bfr = *(const short8*)(krow + kc * 32);
      acc = __builtin_amdgcn_mfma_f32_16x16x32_bf16(qf[kc], bfr, acc, 0, 0, 0);
    }
#pragma unroll
    for (int r = 0; r < 4; ++r) {
      int lrow = rt * 16 + fq * 4 + r;
      int mcol = m0 + ct * 16 + fn;
      size_t gi = poff + (size_t)(l0 + lrow) * 512 + mcol;
      float sv = acc[r] * 0.0625f + prev[gi];
      qk_out[gi] = sv;
      s_bf[lrow * 520 + mcol] = f2bf(sv);
    }
    __syncthreads();
  }

  // ---- softmax over rows (8 threads per row) ----
  {
    int srow = tid >> 3, sseg = tid & 7;
    u16* sp = &s_bf[srow * 520 + sseg * 64];
    float mx = -1e30f;
#pragma unroll
    for (int ii = 0; ii < 8; ++ii) {
      uint4 u = *(const uint4*)(sp + ii * 8);
      mx = fmaxf(mx, fmaxf(fmaxf(fmaxf(bf2f(u.x & 0xffff), bf2f(u.x >> 16)),
                                 fmaxf(bf2f(u.y & 0xffff), bf2f(u.y >> 16))),
                           fmaxf(fmaxf(bf2f(u.z & 0xffff), bf2f(u.z >> 16)),
                                 fmaxf(bf2f(u.w & 0xffff), bf2f(u.w >> 16)))));
    }
#pragma unroll
    for (int o = 1; o < 8; o <<= 1) mx = fmaxf(mx, __shfl_xor(mx, o));
    float sum = 0.f;
#pragma unroll
    for (int ii = 0; ii < 8; ++ii) {
      uint4 u = *(const uint4*)(sp + ii * 8);
      float e0 = __expf(bf2f(u.x & 0xffff) - mx), e1 = __expf(bf2f(u.x >> 16) - mx);
      float e2 = __expf(bf2f(u.y & 0xffff) - mx), e3 = __expf(bf2f(u.y >> 16) - mx);
      float e4 = __expf(bf2f(u.z & 0xffff) - mx), e5 = __expf(bf2f(u.z >> 16) - mx);
      float e6 = __expf(bf2f(u.w & 0xffff) - mx), e7 = __expf(bf2f(u.w >> 16) - mx);
      sum += e0 + e1 + e2 + e3 + e4 + e5 + e6 + e7;
      uint4 o;
      o.x = (u32)f2bf(e0) | ((u32)f2bf(e1) << 16);
      o.y = (u32)f2bf(e2) | ((u32)f2bf(e3) << 16);
      o.z = (u32)f2bf(e4) | ((u32)f2bf(e5) << 16);
      o.w = (u32)f2bf(e6) | ((u32)f2bf(e7) << 16);
      *(uint4*)(sp + ii * 8) = o;
    }
#pragma unroll
    for (int o = 1; o < 8; o <<= 1) sum += __shfl_xor(sum, o);
    if (sseg == 0) rinv[srow] = 1.0f / sum;
  }

  // ---- O = P V ----
  floatx4 oacc[8];
#pragma unroll
  for (int dt = 0; dt < 8; ++dt) oacc[dt] = (floatx4){0.f, 0.f, 0.f, 0.f};

  for (int mc = 0; mc < 16; ++mc) {
    int m0 = mc * 32;
#pragma unroll
    for (int it = 0; it < 4; ++it) {
      int li = it * 256 + tid;
      int d = li >> 2, ms = li & 3;
      *(uint4*)&kv[d * 32 + ms * 8] =
          *(const uint4*)(vt + qoff + (size_t)d * 512 + m0 + ms * 8);
    }
    __syncthreads();
    short8 af = *(const short8*)&s_bf[(rt * 16 + fn) * 520 + m0 + fq * 8];
#pragma unroll
    for (int dt = 0; dt < 8; ++dt) {
      int d0 = ct * 128 + dt * 16;
      short8 bfr = *(const short8*)&kv[(d0 + fn) * 32 + fq * 8];
      oacc[dt] = __builtin_amdgcn_mfma_f32_16x16x32_bf16(af, bfr, oacc[dt], 0, 0, 0);
    }
    __syncthreads();
  }

  float riv[4];
#pragma unroll
  for (int r = 0; r < 4; ++r) riv[r] = rinv[rt * 16 + fq * 4 + r];
#pragma unroll
  for (int dt = 0; dt < 8; ++dt) {
#pragma unroll
    for (int r = 0; r < 4; ++r) {
      int lrow = l0 + rt * 16 + fq * 4 + r;
      int d = ct * 128 + dt * 16 + fn;
      int bl = b * 512 + lrow;
      // w-major a2: feature f = nh*256+d -> [ (f&7)*256 + (f>>3) ]
      a2[(size_t)(bl * 8 + c) * 2048 + ((d & 7) << 8) + (nh << 5) + (d >> 3)] =
          f2bf(oacc[dt][r] * riv[r]);
    }
  }
}

extern "C" void kernel_launch(void* const* d_in, const int* in_sizes, int n_in,
                              void* d_out, int out_size, void* d_ws, size_t ws_size,
                              hipStream_t stream) {
  const float* x    = (const float*)d_in[0];
  const float* prev = (const float*)d_in[1];
  const float* cqw  = (const float*)d_in[2];
  const float* ckw  = (const float*)d_in[3];
  const float* cvw  = (const float*)d_in[4];
  const float* wq   = (const float*)d_in[5];
  const float* wk   = (const float*)d_in[6];
  const float* wv   = (const float*)d_in[7];
  const float* wo   = (const float*)d_in[8];

  float* out    = (float*)d_out;
  float* qk_out = out + 16777216;

  char* wsb = (char*)d_ws;
  u16* wbf    = (u16*)wsb;                         // 4 MB (in old 8 MB slot)
  u16* convq  = (u16*)(wsb + 8388608);             // each 33.5 MB
  u16* convk  = convq + 16777216;
  u16* convv  = convk + 16777216;
  u16* qb     = convv + 16777216;
  u16* kb     = qb + 16777216;
  u16* vb     = kb + 16777216;
  u16* vtb    = vb + 16777216;
  u16* a2     = vtb + 16777216;
  // total ~277 MB

  convert_w_kernel<<<dim3(2048, 4), 256, 0, stream>>>(wq, wk, wv, wo, wbf);
  conv_fused_kernel<<<2048, 256, 0, stream>>>(x, cqw, ckw, cvw, convq, convk, convv);
  mlin_mfma_kernel<0><<<1024, 256, 0, stream>>>(convq, wbf, qb);
  mlin_mfma_kernel<0><<<1024, 256, 0, stream>>>(convk, wbf + 524288, kb);
  mlin_mfma_kernel<1><<<1024, 256, 0, stream>>>(convv, wbf + 1048576, vb);
  transpose_v_kernel<<<4096, 256, 0, stream>>>(vb, vtb);
  attn_kernel<<<2048, 256, 0, stream>>>(qb, kb, vtb, prev, qk_out, a2);
  mlin_mfma_kernel<2><<<1024, 256, 0, stream>>>(a2, wbf + 1572864, out);
}